// Round 13
// baseline (438.203 us; speedup 1.0000x reference)
//
#include <hip/hip_runtime.h>

typedef __bf16 bf16;
typedef __attribute__((ext_vector_type(8))) __bf16 bf16x8;
typedef __attribute__((ext_vector_type(4))) float f32x4;

constexpr int Bb = 4, S = 2048, Dd = 2048, H = 16, G = 4, HD = 128;
constexpr float L2E = 1.4426950408889634f;

__device__ inline f32x4 mfma16(bf16x8 a, bf16x8 b, f32x4 c) {
  return __builtin_amdgcn_mfma_f32_16x16x32_bf16(a, b, c, 0, 0, 0);
}

__device__ inline void gl_lds16(const void* g, void* l) {
  __builtin_amdgcn_global_load_lds(
      (const __attribute__((address_space(1))) void*)g,
      (__attribute__((address_space(3))) void*)l, 16, 0, 0);
}

// ---------------- fp32 -> bf16 elementwise (vectorized) ----------------
__global__ __launch_bounds__(256) void k_f32_to_bf16(
    const float* __restrict__ in, bf16* __restrict__ out, int n8) {
  int i = blockIdx.x * 256 + threadIdx.x;
  if (i >= n8) return;
  const float4* p = (const float4*)(in + (long long)i * 8);
  float4 a = p[0], b = p[1];
  bf16x8 v;
  v[0] = (bf16)a.x; v[1] = (bf16)a.y; v[2] = (bf16)a.z; v[3] = (bf16)a.w;
  v[4] = (bf16)b.x; v[5] = (bf16)b.y; v[6] = (bf16)b.z; v[7] = (bf16)b.w;
  *(bf16x8*)(out + (long long)i * 8) = v;
}

// ---------------- 5 weight transposes in ONE launch ----------------
__global__ __launch_bounds__(256) void k_wtrans(
    const float* __restrict__ wq, const float* __restrict__ wk,
    const float* __restrict__ wv, const float* __restrict__ wg,
    const float* __restrict__ wo, bf16* __restrict__ wcat,
    bf16* __restrict__ woT) {
  __shared__ float tile[32][33];
  const int z = blockIdx.z;
  const float* src;
  bf16* dst;
  int C;
  switch (z) {
    case 0: src = wq; C = 2048; dst = wcat; break;
    case 1: src = wk; C = 512; dst = wcat + (long long)2048 * 2048; break;
    case 2: src = wv; C = 512; dst = wcat + (long long)2560 * 2048; break;
    case 3: src = wg; C = 2048; dst = wcat + (long long)3072 * 2048; break;
    default: src = wo; C = 2048; dst = woT; break;
  }
  int c0 = blockIdx.x * 32, r0 = blockIdx.y * 32;
  if (c0 >= C) return;
  int tx = threadIdx.x, ty = threadIdx.y;
#pragma unroll
  for (int i = 0; i < 4; ++i) {
    int r = r0 + ty + i * 8, c = c0 + tx;
    tile[ty + i * 8][tx] = (c < C) ? src[(long long)r * C + c] : 0.f;
  }
  __syncthreads();
#pragma unroll
  for (int i = 0; i < 4; ++i) {
    int c = c0 + ty + i * 8, r = r0 + tx;
    if (c < C) dst[(long long)c * 2048 + r] = (bf16)tile[tx][ty + i * 8];
  }
}

// ---------------- transpose + convert bf16 (V -> V^T) ----------------
template <typename InT>
__global__ __launch_bounds__(256) void k_transpose_bf16(
    const InT* __restrict__ in, long long s1, int nb2, long long s2, int ldin,
    bf16* __restrict__ out, long long obatch, int ldout, int R, int C) {
  __shared__ float tile[32][33];
  int z = blockIdx.z;
  const InT* ip = in + (long long)(z / nb2) * s1 + (long long)(z % nb2) * s2;
  bf16* op = out + (long long)z * obatch;
  int c0 = blockIdx.x * 32, r0 = blockIdx.y * 32;
  int tx = threadIdx.x, ty = threadIdx.y;
#pragma unroll
  for (int i = 0; i < 4; ++i) {
    int r = r0 + ty + i * 8, c = c0 + tx;
    tile[ty + i * 8][tx] = (r < R && c < C) ? (float)ip[(long long)r * ldin + c] : 0.f;
  }
  __syncthreads();
#pragma unroll
  for (int i = 0; i < 4; ++i) {
    int c = c0 + ty + i * 8, r = r0 + tx;
    if (c < C && r < R) op[(long long)c * ldout + r] = (bf16)tile[tx][ty + i * 8];
  }
}

// ---------------- 256x256 pipelined bf16 GEMM (R12 best-so-far) ------------
template <typename CT, bool SIG>
__global__ __launch_bounds__(512, 1) void k_gemm256(
    const bf16* __restrict__ A, int lda, const bf16* __restrict__ Bt, int ldb,
    CT* __restrict__ C, int ldc, int M, int N, int K, int sig_from) {
  __shared__ bf16 ldsbuf[65536];  // 128 KB
  char* lds2 = (char*)ldsbuf;
  const int tid = threadIdx.x;
  const int w = tid >> 6, lane = tid & 63;
  const int l16 = lane & 15, lh = lane >> 4;
  const int wr = w >> 2, wc = w & 3;
  const int nbn = N >> 8;
  const int cpx = gridDim.x >> 3;
  const int swz = (blockIdx.x & 7) * cpx + (blockIdx.x >> 3);
  const int bm = swz / nbn, bn = swz % nbn;
  const int m0 = bm << 8, n0 = bn << 8;

  const int lrow = lane >> 3;
  const int lcol = ((lane & 7) ^ lrow) * 8;  // pre-swizzled source column
  const int arb = wr * 128 + wc * 16;
  const int xg = wc >> 1, sg = wr * 2 + (wc & 1);
  const int brb = xg * 128 + (sg >> 1) * 64 + (sg & 1) * 16;
  const bf16* aS0 = A + (long long)(m0 + arb + lrow) * lda + lcol;
  const bf16* aS1 = A + (long long)(m0 + arb + 8 + lrow) * lda + lcol;
  const bf16* bS0 = Bt + (long long)(n0 + brb + lrow) * ldb + lcol;
  const bf16* bS1 = Bt + (long long)(n0 + brb + 8 + lrow) * ldb + lcol;

  auto stageA = [&](int buf, int k0, int hi) {
    k0 = (k0 < K) ? k0 : 0;  // clamp: dummy loads keep vmcnt ledger exact
    gl_lds16(aS0 + (long long)hi * 64 * lda + k0,
             lds2 + buf * 65536 + (arb + hi * 64) * 128);
    gl_lds16(aS1 + (long long)hi * 64 * lda + k0,
             lds2 + buf * 65536 + (arb + hi * 64 + 8) * 128);
  };
  auto stageB = [&](int buf, int k0, int hi) {
    k0 = (k0 < K) ? k0 : 0;
    gl_lds16(bS0 + (long long)hi * 32 * ldb + k0,
             lds2 + buf * 65536 + 32768 + (brb + hi * 32) * 128);
    gl_lds16(bS1 + (long long)hi * 32 * ldb + k0,
             lds2 + buf * 65536 + 32768 + (brb + hi * 32 + 8) * 128);
  };

  const int swzc = (l16 & 7) << 4;
  auto rdA = [&](bf16x8 (&dst)[4][2], const char* L, int mh) {
#pragma unroll
    for (int m = 0; m < 4; ++m)
#pragma unroll
      for (int ks = 0; ks < 2; ++ks)
        dst[m][ks] = *(const bf16x8*)(L + (wr * 128 + mh * 64 + m * 16 + l16) * 128 +
                                      ((ks * 64 + lh * 16) ^ swzc));
  };
  auto rdB = [&](bf16x8 (&dst)[2][2], const char* L, int nh) {
#pragma unroll
    for (int n = 0; n < 2; ++n)
#pragma unroll
      for (int ks = 0; ks < 2; ++ks)
        dst[n][ks] = *(const bf16x8*)(L + 32768 + (wc * 64 + nh * 32 + n * 16 + l16) * 128 +
                                      ((ks * 64 + lh * 16) ^ swzc));
  };

  f32x4 acc[8][4] = {};
  bf16x8 aflo[4][2], afhi[4][2], bn0[2][2], bn1[2][2];
  const int NT = K >> 6;

  // prologue: 12 loads in steady-state-mimicking order
  stageA(0, 0, 0);
  stageB(0, 0, 0);
  stageB(0, 0, 1);
  stageA(0, 0, 1);
  stageA(1, 64, 0);
  stageB(1, 64, 0);
  asm volatile("s_waitcnt vmcnt(4)" ::: "memory");
  __builtin_amdgcn_s_barrier();
  asm volatile("" ::: "memory");
  rdA(aflo, lds2, 0);
  rdB(bn0, lds2, 0);

  for (int t = 0; t < NT; ++t) {
    const int buf = t & 1, nb = buf ^ 1;
    const char* L = lds2 + buf * 65536;
    const char* Ln = lds2 + nb * 65536;
    const int k1 = (t + 1) << 6;
    const int k2 = (t + 2) << 6;
    const bool more = (t + 1 < NT);
    // ---- Q1: MFMA mlo x n01; read bn1(t); stage SB1(t+1) ----
    stageB(nb, k1, 1);
    rdB(bn1, L, 1);
    __builtin_amdgcn_s_setprio(1);
#pragma unroll
    for (int ks = 0; ks < 2; ++ks)
#pragma unroll
      for (int m = 0; m < 4; ++m)
#pragma unroll
        for (int n = 0; n < 2; ++n)
          acc[m][n] = mfma16(aflo[m][ks], bn0[n][ks], acc[m][n]);
    __builtin_amdgcn_s_setprio(0);
    asm volatile("s_waitcnt vmcnt(6)" ::: "memory");  // drains SA1(t)
    __builtin_amdgcn_s_barrier();
    asm volatile("" ::: "memory");
    // ---- Q2: MFMA mlo x n23; read afhi(t); stage SA1(t+1) ----
    stageA(nb, k1, 1);
    rdA(afhi, L, 1);
    __builtin_amdgcn_s_setprio(1);
#pragma unroll
    for (int ks = 0; ks < 2; ++ks)
#pragma unroll
      for (int m = 0; m < 4; ++m)
#pragma unroll
        for (int n = 0; n < 2; ++n)
          acc[m][2 + n] = mfma16(aflo[m][ks], bn1[n][ks], acc[m][2 + n]);
    __builtin_amdgcn_s_setprio(0);
    __builtin_amdgcn_s_barrier();
    asm volatile("" ::: "memory");
    // ---- Q3: MFMA mhi x n23; stage SA0(t+2) ----
    stageA(buf, k2, 0);
    __builtin_amdgcn_s_setprio(1);
#pragma unroll
    for (int ks = 0; ks < 2; ++ks)
#pragma unroll
      for (int m = 0; m < 4; ++m)
#pragma unroll
        for (int n = 0; n < 2; ++n)
          acc[4 + m][2 + n] = mfma16(afhi[m][ks], bn1[n][ks], acc[4 + m][2 + n]);
    __builtin_amdgcn_s_setprio(0);
    asm volatile("s_waitcnt vmcnt(6)" ::: "memory");  // drains SA0(t+1),SB0(t+1)
    __builtin_amdgcn_s_barrier();
    asm volatile("" ::: "memory");
    // ---- Q4: MFMA mhi x n01; read aflo/bn0(t+1); stage SB0(t+2) ----
    if (more) rdA(aflo, Ln, 0);
    stageB(buf, k2, 0);
    __builtin_amdgcn_s_setprio(1);
#pragma unroll
    for (int ks = 0; ks < 2; ++ks)
#pragma unroll
      for (int m = 0; m < 4; ++m)
#pragma unroll
        for (int n = 0; n < 2; ++n)
          acc[4 + m][n] = mfma16(afhi[m][ks], bn0[n][ks], acc[4 + m][n]);
    __builtin_amdgcn_s_setprio(0);
    if (more) rdB(bn0, Ln, 0);  // WAR on bn0 keeps this after the MFMAs
    asm volatile("s_waitcnt vmcnt(6)" ::: "memory");  // drains SB1(t+1)
    __builtin_amdgcn_s_barrier();
    asm volatile("" ::: "memory");
  }

#pragma unroll
  for (int m = 0; m < 8; ++m)
#pragma unroll
    for (int n = 0; n < 4; ++n) {
      const int col = n0 + wc * 64 + n * 16 + l16;
#pragma unroll
      for (int r = 0; r < 4; ++r) {
        float v = acc[m][n][r];
        if (SIG && col >= sig_from) v = 1.f / (1.f + exp2f(-v * L2E));
        C[(long long)(m0 + wr * 128 + m * 16 + lh * 4 + r) * ldc + col] = (CT)v;
      }
    }
}

// ---------------- RMSNorm + RoPE, Q and K in one launch ----------------
__global__ __launch_bounds__(256) void k_rms_rope2(
    const bf16* __restrict__ C1, const float* __restrict__ qs,
    const float* __restrict__ ksc, const float* __restrict__ cosT,
    const float* __restrict__ sinT, bf16* __restrict__ qb,
    bf16* __restrict__ kb) {
  int wid = (blockIdx.x * 256 + threadIdx.x) >> 6;
  int lane = threadIdx.x & 63;
  const bf16* ip;
  const float* scale;
  bf16* op;
  float oscale;
  int s;
  if (wid < 131072) {  // Q
    int h = wid & 15, bs = wid >> 4;
    s = bs & 2047;
    int b = bs >> 11;
    ip = C1 + (long long)bs * 5120 + h * HD;
    scale = qs;
    oscale = 0.12751879523209308f;  // L2E / sqrt(HD)
    op = qb + (((long long)b * H + h) * S + s) * HD;
  } else {  // K
    wid -= 131072;
    int h = wid & 3, bs = wid >> 2;
    s = bs & 2047;
    int b = bs >> 11;
    ip = C1 + 2048 + (long long)bs * 5120 + h * HD;
    scale = ksc;
    oscale = 1.0f;
    op = kb + (((long long)b * G + h) * S + s) * HD;
  }
  float x1 = (float)ip[lane], x2 = (float)ip[lane + 64];
  float ss = x1 * x1 + x2 * x2;
#pragma unroll
  for (int m = 1; m < 64; m <<= 1) ss += __shfl_xor(ss, m);
  float rms = rsqrtf(ss * (1.f / 128.f) + 1e-6f);
  float n1 = x1 * rms * (1.f + scale[lane]);
  float n2 = x2 * rms * (1.f + scale[lane + 64]);
  float o1 = (n1 * cosT[s * 128 + lane] - n2 * sinT[s * 128 + lane]) * oscale;
  float o2 = (n2 * cosT[s * 128 + lane + 64] + n1 * sinT[s * 128 + lane + 64]) * oscale;
  op[lane] = (bf16)o1;
  op[lane + 64] = (bf16)o2;
}

// ---------------- causal GQA flash attention v6 ----------------
// V double-buffered: LDS = Ks 32K + Vs 32K + Ps 16K = 80KB (2 blocks/CU).
// ONE barrier per tile (was two): stage V(t+1)/K(t+1) -> QK^T -> softmax ->
// PV (V staged a full tile ahead) -> vmcnt(0)+barrier. Ps is per-wave (RAW
// handled by lgkmcnt). Inactive tiles still stage+barrier (uniform counts).
__global__ __launch_bounds__(256, 2) void k_flash6(
    const bf16* __restrict__ Q, const bf16* __restrict__ Kb,
    const bf16* __restrict__ Vt, const bf16* __restrict__ gate, int ldg,
    bf16* __restrict__ outc, int ldo) {
  __shared__ bf16 Ks[2][64 * 128];  // [kv][d], byte ^= (kv&7)<<4
  __shared__ bf16 Vs[2][128 * 64];  // [d][kv], byte ^= (d&7)<<4
  __shared__ bf16 Ps[4][32 * 64];   // per-wave P, byte ^= (row&7)<<4
  const int tid = threadIdx.x, w = tid >> 6, lane = tid & 63;
  const int l16 = lane & 15, lh = lane >> 4;
  const int bh = blockIdx.x & 63;
  const int qi = blockIdx.x >> 6;   // 0..15
  const int qc = 15 - qi;           // heavy chunks first (LPT)
  const int h = bh & 15, b = bh >> 4, g = h >> 2;
  const int q0w = qc * 128 + w * 32;
  const bf16* qp = Q + (((long long)b * H + h) * S + q0w) * HD;
  const bf16* kp = Kb + ((long long)b * G + g) * S * HD;
  const bf16* vp = Vt + ((long long)b * G + g) * (long long)HD * S;

  bf16x8 aq[2][4];
#pragma unroll
  for (int m = 0; m < 2; ++m)
#pragma unroll
    for (int ks = 0; ks < 4; ++ks)
      aq[m][ks] = *(const bf16x8*)(qp + (long long)(m * 16 + l16) * HD + ks * 32 + lh * 8);

  f32x4 acc[2][8] = {};
  float mrow[2][4], lrow[2][4];
#pragma unroll
  for (int m = 0; m < 2; ++m)
#pragma unroll
    for (int r = 0; r < 4; ++r) { mrow[m][r] = -1e30f; lrow[m][r] = 0.f; }

  const int ntiles = qc * 2 + 2;

  auto stageK = [&](int bi, int t) {
    const int kv0 = t << 6;
#pragma unroll
    for (int i = 0; i < 4; ++i) {
      int c = w * 256 + i * 64 + lane;  // 1024 16B-chunks
      int row = c >> 4;
      int cb = ((c & 15) << 4) ^ ((row & 7) << 4);
      gl_lds16(kp + (long long)(kv0 + row) * HD + (cb >> 1),
               (char*)Ks[bi] + (w * 256 + i * 64) * 16);
    }
  };
  auto stageV = [&](int bi, int t) {
    const int kv0 = t << 6;
#pragma unroll
    for (int i = 0; i < 4; ++i) {
      int c = w * 256 + i * 64 + lane;
      int rowv = c >> 3;
      int cbv = ((c & 7) << 4) ^ ((rowv & 7) << 4);
      gl_lds16(vp + (long long)rowv * S + kv0 + (cbv >> 1),
               (char*)Vs[bi] + (w * 256 + i * 64) * 16);
    }
  };

  // prologue: K(0) and V(0) into buf0
  stageK(0, 0);
  stageV(0, 0);
  asm volatile("s_waitcnt vmcnt(0)" ::: "memory");
  __builtin_amdgcn_s_barrier();
  asm volatile("" ::: "memory");

  for (int t = 0; t < ntiles; ++t) {
    const int buf = t & 1, nb = buf ^ 1;
    const int kv0 = t << 6;
    const bool active = (kv0 <= q0w + 31);
    const int tn = (t + 1 < ntiles) ? t + 1 : t;  // clamped dummy on last tile
    stageV(nb, tn);
    stageK(nb, tn);
    if (active) {
      // ---- QK^T from Ks[buf] ----
      f32x4 s[2][4] = {};
#pragma unroll
      for (int ks = 0; ks < 4; ++ks)
#pragma unroll
        for (int n = 0; n < 4; ++n) {
          int row = n * 16 + l16;
          int off = row * 256 + ((ks * 64 + lh * 16) ^ ((row & 7) << 4));
          bf16x8 kb = *(const bf16x8*)((const char*)Ks[buf] + off);
#pragma unroll
          for (int m = 0; m < 2; ++m) s[m][n] = mfma16(aq[m][ks], kb, s[m][n]);
        }
      // ---- causal mask ----
      if (kv0 + 63 > q0w) {
#pragma unroll
        for (int m = 0; m < 2; ++m)
#pragma unroll
          for (int n = 0; n < 4; ++n)
#pragma unroll
            for (int r = 0; r < 4; ++r) {
              int col = kv0 + n * 16 + l16;
              int rowg = q0w + m * 16 + lh * 4 + r;
              if (col > rowg) s[m][n][r] = -1e30f;
            }
      }
      // ---- online softmax (defer-max THR=8, log2 domain) ----
      float lm[2][4];
      bool okl = true;
#pragma unroll
      for (int m = 0; m < 2; ++m)
#pragma unroll
        for (int r = 0; r < 4; ++r) {
          lm[m][r] = fmaxf(fmaxf(s[m][0][r], s[m][1][r]), fmaxf(s[m][2][r], s[m][3][r]));
          okl = okl && (lm[m][r] <= mrow[m][r] + 8.f);
        }
      if (!__all(okl)) {
#pragma unroll
        for (int st = 1; st < 16; st <<= 1)
#pragma unroll
          for (int m = 0; m < 2; ++m)
#pragma unroll
            for (int r = 0; r < 4; ++r) lm[m][r] = fmaxf(lm[m][r], __shfl_xor(lm[m][r], st));
#pragma unroll
        for (int m = 0; m < 2; ++m)
#pragma unroll
          for (int r = 0; r < 4; ++r) {
            float mn = fmaxf(mrow[m][r], lm[m][r]);
            float resc = exp2f(mrow[m][r] - mn);
            mrow[m][r] = mn;
            lrow[m][r] *= resc;
#pragma unroll
            for (int dt = 0; dt < 8; ++dt) acc[m][dt][r] *= resc;
          }
      }
      // ---- P = exp2(s - m), store swizzled, accumulate l ----
#pragma unroll
      for (int m = 0; m < 2; ++m)
#pragma unroll
        for (int n = 0; n < 4; ++n)
#pragma unroll
          for (int r = 0; r < 4; ++r) {
            float p = exp2f(s[m][n][r] - mrow[m][r]);
            s[m][n][r] = p;
            int row = m * 16 + lh * 4 + r;
            *(bf16*)((char*)Ps[w] + row * 128 +
                     ((n * 32 + l16 * 2) ^ ((row & 7) << 4))) = (bf16)p;
          }
#pragma unroll
      for (int m = 0; m < 2; ++m)
#pragma unroll
        for (int r = 0; r < 4; ++r)
          lrow[m][r] += s[m][0][r] + s[m][1][r] + s[m][2][r] + s[m][3][r];
      // ---- PV from Vs[buf] (staged a full tile ago; no wait needed) ----
      bf16x8 pa[2][2];
#pragma unroll
      for (int m = 0; m < 2; ++m)
#pragma unroll
        for (int kf = 0; kf < 2; ++kf) {
          int row = m * 16 + l16;
          pa[m][kf] = *(const bf16x8*)((const char*)Ps[w] + row * 128 +
                                       ((kf * 64 + lh * 16) ^ ((row & 7) << 4)));
        }
#pragma unroll
      for (int kf = 0; kf < 2; ++kf)
#pragma unroll
        for (int dt = 0; dt < 8; ++dt) {
          int d = dt * 16 + l16;
          int off = d * 128 + ((kf * 64 + lh * 16) ^ ((d & 7) << 4));
          bf16x8 vb = *(const bf16x8*)((const char*)Vs[buf] + off);
#pragma unroll
          for (int m = 0; m < 2; ++m) acc[m][dt] = mfma16(pa[m][kf], vb, acc[m][dt]);
        }
    }
    // ---- single tile-end sync: V(t+1),K(t+1) resident; bufs swap safe ----
    asm volatile("s_waitcnt vmcnt(0)" ::: "memory");
    __builtin_amdgcn_s_barrier();
    asm volatile("" ::: "memory");
  }

#pragma unroll
  for (int st = 1; st < 16; st <<= 1)
#pragma unroll
    for (int m = 0; m < 2; ++m)
#pragma unroll
      for (int r = 0; r < 4; ++r) lrow[m][r] += __shfl_xor(lrow[m][r], st);
  float inv[2][4];
#pragma unroll
  for (int m = 0; m < 2; ++m)
#pragma unroll
    for (int r = 0; r < 4; ++r) inv[m][r] = 1.f / lrow[m][r];
#pragma unroll
  for (int m = 0; m < 2; ++m)
#pragma unroll
    for (int dt = 0; dt < 8; ++dt)
#pragma unroll
      for (int r = 0; r < 4; ++r) {
        int rowg = q0w + m * 16 + lh * 4 + r;
        long long row = (long long)b * S + rowg;
        int col = h * HD + dt * 16 + l16;
        float gv = (float)gate[row * ldg + col];
        outc[row * ldo + col] = (bf16)(acc[m][dt][r] * inv[m][r] * gv);
      }
}

extern "C" void kernel_launch(void* const* d_in, const int* in_sizes, int n_in,
                              void* d_out, int out_size, void* d_ws, size_t ws_size,
                              hipStream_t stream) {
  const float* x = (const float*)d_in[0];
  const float* cosT = (const float*)d_in[2];
  const float* sinT = (const float*)d_in[3];
  const float* wq = (const float*)d_in[4];
  const float* wk = (const float*)d_in[5];
  const float* wv = (const float*)d_in[6];
  const float* wg = (const float*)d_in[7];
  const float* wo = (const float*)d_in[8];
  const float* qs = (const float*)d_in[9];
  const float* ksc = (const float*)d_in[10];
  float* out = (float*)d_out;
  char* ws = (char*)d_ws;

  if (ws_size < 146800640) return;
  bf16* xb = (bf16*)(ws);
  bf16* wcat = (bf16*)(ws + 33554432);
  bf16* woT = (bf16*)(ws + 54525952);
  bf16* C1 = (bf16*)(ws + 62914560);
  bf16* qbuf = xb;
  bf16* kbuf = wcat;
  bf16* vtbuf = wcat + 4194304;
  bf16* gatep = C1 + 3072;
  bf16* ctxg = C1;

  dim3 tb(32, 8);
  k_f32_to_bf16<<<8192, 256, 0, stream>>>(x, xb, Bb * S * Dd / 8);
  k_wtrans<<<dim3(64, 64, 5), tb, 0, stream>>>(wq, wk, wv, wg, wo, wcat, woT);
  // fused QKVG GEMM + sigmoid on gate cols (>=3072)
  k_gemm256<bf16, true><<<32 * 20, 512, 0, stream>>>(
      xb, 2048, wcat, 2048, C1, 5120, 8192, 5120, 2048, 3072);
  // RMSNorm + RoPE for Q and K (L2E/sqrt(HD) folded into Q)
  k_rms_rope2<<<40960, 256, 0, stream>>>(C1, qs, ksc, cosT, sinT, qbuf, kbuf);
  // V -> V^T (B,G,128,S)
  k_transpose_bf16<bf16><<<dim3(4, 64, 16), tb, 0, stream>>>(
      C1 + 2560, (long long)2048 * 5120, 4, 128, 5120, vtbuf,
      (long long)128 * 2048, 2048, 2048, 128);
  // flash attention v6 (V-dbuf, 1 barrier/tile) + gate -> C1 cols 0:2048
  k_flash6<<<1024, 256, 0, stream>>>(qbuf, kbuf, vtbuf, gatep, 5120, ctxg, 5120);
  // output GEMM
  k_gemm256<float, false><<<32 * 8, 512, 0, stream>>>(
      ctxg, 5120, woT, 2048, out, 2048, 8192, 2048, 2048, 1 << 30);
}

// Round 14
// 429.873 us; speedup vs baseline: 1.0194x; 1.0194x over previous
//
#include <hip/hip_runtime.h>

typedef __bf16 bf16;
typedef __attribute__((ext_vector_type(8))) __bf16 bf16x8;
typedef __attribute__((ext_vector_type(4))) float f32x4;

constexpr int Bb = 4, S = 2048, Dd = 2048, H = 16, G = 4, HD = 128;
constexpr float L2E = 1.4426950408889634f;

__device__ inline f32x4 mfma16(bf16x8 a, bf16x8 b, f32x4 c) {
  return __builtin_amdgcn_mfma_f32_16x16x32_bf16(a, b, c, 0, 0, 0);
}

__device__ inline void gl_lds16(const void* g, void* l) {
  __builtin_amdgcn_global_load_lds(
      (const __attribute__((address_space(1))) void*)g,
      (__attribute__((address_space(3))) void*)l, 16, 0, 0);
}

// ---------------- pre: x->bf16 (z=5) + 5 weight transposes (z=0..4) -------
// One launch; independent memory-bound ops overlap instead of serializing.
__global__ __launch_bounds__(256) void k_pre(
    const float* __restrict__ x, const float* __restrict__ wq,
    const float* __restrict__ wk, const float* __restrict__ wv,
    const float* __restrict__ wg, const float* __restrict__ wo,
    bf16* __restrict__ xb, bf16* __restrict__ wcat, bf16* __restrict__ woT) {
  const int z = blockIdx.z;
  const int tx = threadIdx.x, ty = threadIdx.y;
  const int tid = ty * 32 + tx;
  if (z == 5) {
    // x -> bf16: 4096 linear blocks x 256 thr x 2 vec8 = 2,097,152 vec8s
    const long long blk = (long long)blockIdx.y * 64 + blockIdx.x;
    long long i = blk * 256 + tid;
#pragma unroll
    for (int rep = 0; rep < 2; ++rep, i += 1048576) {
      const float4* p = (const float4*)(x + i * 8);
      float4 a = p[0], b = p[1];
      bf16x8 v;
      v[0] = (bf16)a.x; v[1] = (bf16)a.y; v[2] = (bf16)a.z; v[3] = (bf16)a.w;
      v[4] = (bf16)b.x; v[5] = (bf16)b.y; v[6] = (bf16)b.z; v[7] = (bf16)b.w;
      *(bf16x8*)(xb + i * 8) = v;
    }
    return;
  }
  __shared__ float tile[32][33];
  const float* src;
  bf16* dst;
  int C;
  switch (z) {
    case 0: src = wq; C = 2048; dst = wcat; break;
    case 1: src = wk; C = 512; dst = wcat + (long long)2048 * 2048; break;
    case 2: src = wv; C = 512; dst = wcat + (long long)2560 * 2048; break;
    case 3: src = wg; C = 2048; dst = wcat + (long long)3072 * 2048; break;
    default: src = wo; C = 2048; dst = woT; break;
  }
  int c0 = blockIdx.x * 32, r0 = blockIdx.y * 32;
  if (c0 >= C) return;
#pragma unroll
  for (int i = 0; i < 4; ++i) {
    int r = r0 + ty + i * 8, c = c0 + tx;
    tile[ty + i * 8][tx] = (c < C) ? src[(long long)r * C + c] : 0.f;
  }
  __syncthreads();
#pragma unroll
  for (int i = 0; i < 4; ++i) {
    int c = c0 + ty + i * 8, r = r0 + tx;
    if (c < C) dst[(long long)c * 2048 + r] = (bf16)tile[tx][ty + i * 8];
  }
}

// ---------------- 256x256 pipelined bf16 GEMM (R12 best-so-far) ------------
template <typename CT, bool SIG>
__global__ __launch_bounds__(512, 1) void k_gemm256(
    const bf16* __restrict__ A, int lda, const bf16* __restrict__ Bt, int ldb,
    CT* __restrict__ C, int ldc, int M, int N, int K, int sig_from) {
  __shared__ bf16 ldsbuf[65536];  // 128 KB
  char* lds2 = (char*)ldsbuf;
  const int tid = threadIdx.x;
  const int w = tid >> 6, lane = tid & 63;
  const int l16 = lane & 15, lh = lane >> 4;
  const int wr = w >> 2, wc = w & 3;
  const int nbn = N >> 8;
  const int cpx = gridDim.x >> 3;
  const int swz = (blockIdx.x & 7) * cpx + (blockIdx.x >> 3);
  const int bm = swz / nbn, bn = swz % nbn;
  const int m0 = bm << 8, n0 = bn << 8;

  const int lrow = lane >> 3;
  const int lcol = ((lane & 7) ^ lrow) * 8;  // pre-swizzled source column
  const int arb = wr * 128 + wc * 16;
  const int xg = wc >> 1, sg = wr * 2 + (wc & 1);
  const int brb = xg * 128 + (sg >> 1) * 64 + (sg & 1) * 16;
  const bf16* aS0 = A + (long long)(m0 + arb + lrow) * lda + lcol;
  const bf16* aS1 = A + (long long)(m0 + arb + 8 + lrow) * lda + lcol;
  const bf16* bS0 = Bt + (long long)(n0 + brb + lrow) * ldb + lcol;
  const bf16* bS1 = Bt + (long long)(n0 + brb + 8 + lrow) * ldb + lcol;

  auto stageA = [&](int buf, int k0, int hi) {
    k0 = (k0 < K) ? k0 : 0;  // clamp: dummy loads keep vmcnt ledger exact
    gl_lds16(aS0 + (long long)hi * 64 * lda + k0,
             lds2 + buf * 65536 + (arb + hi * 64) * 128);
    gl_lds16(aS1 + (long long)hi * 64 * lda + k0,
             lds2 + buf * 65536 + (arb + hi * 64 + 8) * 128);
  };
  auto stageB = [&](int buf, int k0, int hi) {
    k0 = (k0 < K) ? k0 : 0;
    gl_lds16(bS0 + (long long)hi * 32 * ldb + k0,
             lds2 + buf * 65536 + 32768 + (brb + hi * 32) * 128);
    gl_lds16(bS1 + (long long)hi * 32 * ldb + k0,
             lds2 + buf * 65536 + 32768 + (brb + hi * 32 + 8) * 128);
  };

  const int swzc = (l16 & 7) << 4;
  auto rdA = [&](bf16x8 (&dst)[4][2], const char* L, int mh) {
#pragma unroll
    for (int m = 0; m < 4; ++m)
#pragma unroll
      for (int ks = 0; ks < 2; ++ks)
        dst[m][ks] = *(const bf16x8*)(L + (wr * 128 + mh * 64 + m * 16 + l16) * 128 +
                                      ((ks * 64 + lh * 16) ^ swzc));
  };
  auto rdB = [&](bf16x8 (&dst)[2][2], const char* L, int nh) {
#pragma unroll
    for (int n = 0; n < 2; ++n)
#pragma unroll
      for (int ks = 0; ks < 2; ++ks)
        dst[n][ks] = *(const bf16x8*)(L + 32768 + (wc * 64 + nh * 32 + n * 16 + l16) * 128 +
                                      ((ks * 64 + lh * 16) ^ swzc));
  };

  f32x4 acc[8][4] = {};
  bf16x8 aflo[4][2], afhi[4][2], bn0[2][2], bn1[2][2];
  const int NT = K >> 6;

  // prologue: 12 loads in steady-state-mimicking order
  stageA(0, 0, 0);
  stageB(0, 0, 0);
  stageB(0, 0, 1);
  stageA(0, 0, 1);
  stageA(1, 64, 0);
  stageB(1, 64, 0);
  asm volatile("s_waitcnt vmcnt(4)" ::: "memory");
  __builtin_amdgcn_s_barrier();
  asm volatile("" ::: "memory");
  rdA(aflo, lds2, 0);
  rdB(bn0, lds2, 0);

  for (int t = 0; t < NT; ++t) {
    const int buf = t & 1, nb = buf ^ 1;
    const char* L = lds2 + buf * 65536;
    const char* Ln = lds2 + nb * 65536;
    const int k1 = (t + 1) << 6;
    const int k2 = (t + 2) << 6;
    const bool more = (t + 1 < NT);
    // ---- Q1: MFMA mlo x n01; read bn1(t); stage SB1(t+1) ----
    stageB(nb, k1, 1);
    rdB(bn1, L, 1);
    __builtin_amdgcn_s_setprio(1);
#pragma unroll
    for (int ks = 0; ks < 2; ++ks)
#pragma unroll
      for (int m = 0; m < 4; ++m)
#pragma unroll
        for (int n = 0; n < 2; ++n)
          acc[m][n] = mfma16(aflo[m][ks], bn0[n][ks], acc[m][n]);
    __builtin_amdgcn_s_setprio(0);
    asm volatile("s_waitcnt vmcnt(6)" ::: "memory");  // drains SA1(t)
    __builtin_amdgcn_s_barrier();
    asm volatile("" ::: "memory");
    // ---- Q2: MFMA mlo x n23; read afhi(t); stage SA1(t+1) ----
    stageA(nb, k1, 1);
    rdA(afhi, L, 1);
    __builtin_amdgcn_s_setprio(1);
#pragma unroll
    for (int ks = 0; ks < 2; ++ks)
#pragma unroll
      for (int m = 0; m < 4; ++m)
#pragma unroll
        for (int n = 0; n < 2; ++n)
          acc[m][2 + n] = mfma16(aflo[m][ks], bn1[n][ks], acc[m][2 + n]);
    __builtin_amdgcn_s_setprio(0);
    __builtin_amdgcn_s_barrier();
    asm volatile("" ::: "memory");
    // ---- Q3: MFMA mhi x n23; stage SA0(t+2) ----
    stageA(buf, k2, 0);
    __builtin_amdgcn_s_setprio(1);
#pragma unroll
    for (int ks = 0; ks < 2; ++ks)
#pragma unroll
      for (int m = 0; m < 4; ++m)
#pragma unroll
        for (int n = 0; n < 2; ++n)
          acc[4 + m][2 + n] = mfma16(afhi[m][ks], bn1[n][ks], acc[4 + m][2 + n]);
    __builtin_amdgcn_s_setprio(0);
    asm volatile("s_waitcnt vmcnt(6)" ::: "memory");  // drains SA0(t+1),SB0(t+1)
    __builtin_amdgcn_s_barrier();
    asm volatile("" ::: "memory");
    // ---- Q4: MFMA mhi x n01; read aflo/bn0(t+1); stage SB0(t+2) ----
    if (more) rdA(aflo, Ln, 0);
    stageB(buf, k2, 0);
    __builtin_amdgcn_s_setprio(1);
#pragma unroll
    for (int ks = 0; ks < 2; ++ks)
#pragma unroll
      for (int m = 0; m < 4; ++m)
#pragma unroll
        for (int n = 0; n < 2; ++n)
          acc[4 + m][n] = mfma16(afhi[m][ks], bn0[n][ks], acc[4 + m][n]);
    __builtin_amdgcn_s_setprio(0);
    if (more) rdB(bn0, Ln, 0);  // WAR on bn0 keeps this after the MFMAs
    asm volatile("s_waitcnt vmcnt(6)" ::: "memory");  // drains SB1(t+1)
    __builtin_amdgcn_s_barrier();
    asm volatile("" ::: "memory");
  }

#pragma unroll
  for (int m = 0; m < 8; ++m)
#pragma unroll
    for (int n = 0; n < 4; ++n) {
      const int col = n0 + wc * 64 + n * 16 + l16;
#pragma unroll
      for (int r = 0; r < 4; ++r) {
        float v = acc[m][n][r];
        if (SIG && col >= sig_from) v = 1.f / (1.f + exp2f(-v * L2E));
        C[(long long)(m0 + wr * 128 + m * 16 + lh * 4 + r) * ldc + col] = (CT)v;
      }
    }
}

// ---------------- post: RMSNorm+RoPE (Q,K) + V->V^T, one launch ------------
// blocks [0,40960): rope waves; blocks [40960,45056): V-transpose tiles.
__global__ __launch_bounds__(256) void k_post(
    const bf16* __restrict__ C1, const float* __restrict__ qs,
    const float* __restrict__ ksc, const float* __restrict__ cosT,
    const float* __restrict__ sinT, bf16* __restrict__ qb,
    bf16* __restrict__ kb, bf16* __restrict__ vtbuf) {
  __shared__ float tile[32][33];
  const int bx = blockIdx.x;
  const int tid = threadIdx.x;
  if (bx < 40960) {
    int wid = (bx * 256 + tid) >> 6;
    int lane = tid & 63;
    const bf16* ip;
    const float* scale;
    bf16* op;
    float oscale;
    int s;
    if (wid < 131072) {  // Q
      int h = wid & 15, bs = wid >> 4;
      s = bs & 2047;
      int b = bs >> 11;
      ip = C1 + (long long)bs * 5120 + h * HD;
      scale = qs;
      oscale = 0.12751879523209308f;  // L2E / sqrt(HD)
      op = qb + (((long long)b * H + h) * S + s) * HD;
    } else {  // K
      wid -= 131072;
      int h = wid & 3, bs = wid >> 2;
      s = bs & 2047;
      int b = bs >> 11;
      ip = C1 + 2048 + (long long)bs * 5120 + h * HD;
      scale = ksc;
      oscale = 1.0f;
      op = kb + (((long long)b * G + h) * S + s) * HD;
    }
    float x1 = (float)ip[lane], x2 = (float)ip[lane + 64];
    float ss = x1 * x1 + x2 * x2;
#pragma unroll
    for (int m = 1; m < 64; m <<= 1) ss += __shfl_xor(ss, m);
    float rms = rsqrtf(ss * (1.f / 128.f) + 1e-6f);
    float n1 = x1 * rms * (1.f + scale[lane]);
    float n2 = x2 * rms * (1.f + scale[lane + 64]);
    float o1 = (n1 * cosT[s * 128 + lane] - n2 * sinT[s * 128 + lane]) * oscale;
    float o2 = (n2 * cosT[s * 128 + lane + 64] + n1 * sinT[s * 128 + lane + 64]) * oscale;
    op[lane] = (bf16)o1;
    op[lane + 64] = (bf16)o2;
    return;
  }
  // V -> V^T: zb decodes original dim3(4,64,16) grid; tx/ty from flat tid.
  const int zb = bx - 40960;
  const int gx = zb & 3, gy = (zb >> 2) & 63, gz = zb >> 8;  // (x,y,z)
  const int tx = tid & 31, ty = tid >> 5;
  const bf16* ip = C1 + 2560 + (long long)(gz >> 2) * (2048LL * 5120) +
                   (long long)(gz & 3) * 128;
  bf16* op = vtbuf + (long long)gz * (128LL * 2048);
  int c0 = gx * 32, r0 = gy * 32;
#pragma unroll
  for (int i = 0; i < 4; ++i) {
    int r = r0 + ty + i * 8, c = c0 + tx;
    tile[ty + i * 8][tx] = (float)ip[(long long)r * 5120 + c];
  }
  __syncthreads();
#pragma unroll
  for (int i = 0; i < 4; ++i) {
    int c = c0 + ty + i * 8, r = r0 + tx;
    op[(long long)c * 2048 + r] = (bf16)tile[tx][ty + i * 8];
  }
}

// ---------------- causal GQA flash attention v5 (R12 known-good) -----------
__global__ __launch_bounds__(256, 2) void k_flash5(
    const bf16* __restrict__ Q, const bf16* __restrict__ Kb,
    const bf16* __restrict__ Vt, const bf16* __restrict__ gate, int ldg,
    bf16* __restrict__ outc, int ldo) {
  __shared__ bf16 Ks[2][64 * 128];  // [kv][d], byte ^= (kv&7)<<4
  __shared__ bf16 Vs[128 * 64];     // [d][kv], byte ^= (d&7)<<4
  __shared__ bf16 Ps[4][32 * 64];   // per-wave P, byte ^= (row&7)<<4
  const int tid = threadIdx.x, w = tid >> 6, lane = tid & 63;
  const int l16 = lane & 15, lh = lane >> 4;
  const int bh = blockIdx.x & 63;
  const int qi = blockIdx.x >> 6;   // 0..15
  const int qc = 15 - qi;           // heavy chunks first (LPT)
  const int h = bh & 15, b = bh >> 4, g = h >> 2;
  const int q0w = qc * 128 + w * 32;
  const bf16* qp = Q + (((long long)b * H + h) * S + q0w) * HD;
  const bf16* kp = Kb + ((long long)b * G + g) * S * HD;
  const bf16* vp = Vt + ((long long)b * G + g) * (long long)HD * S;

  bf16x8 aq[2][4];
#pragma unroll
  for (int m = 0; m < 2; ++m)
#pragma unroll
    for (int ks = 0; ks < 4; ++ks)
      aq[m][ks] = *(const bf16x8*)(qp + (long long)(m * 16 + l16) * HD + ks * 32 + lh * 8);

  f32x4 acc[2][8] = {};
  float mrow[2][4], lrow[2][4];
#pragma unroll
  for (int m = 0; m < 2; ++m)
#pragma unroll
    for (int r = 0; r < 4; ++r) { mrow[m][r] = -1e30f; lrow[m][r] = 0.f; }

  const int ntiles = qc * 2 + 2;

  auto stageK = [&](int bi, int t) {
    const int kv0 = t << 6;
#pragma unroll
    for (int i = 0; i < 4; ++i) {
      int c = w * 256 + i * 64 + lane;  // 1024 16B-chunks
      int row = c >> 4;
      int cb = ((c & 15) << 4) ^ ((row & 7) << 4);
      gl_lds16(kp + (long long)(kv0 + row) * HD + (cb >> 1),
               (char*)Ks[bi] + (w * 256 + i * 64) * 16);
    }
  };
  auto stageV = [&](int t) {
    const int kv0 = t << 6;
#pragma unroll
    for (int i = 0; i < 4; ++i) {
      int c = w * 256 + i * 64 + lane;
      int rowv = c >> 3;
      int cbv = ((c & 7) << 4) ^ ((rowv & 7) << 4);
      gl_lds16(vp + (long long)rowv * S + kv0 + (cbv >> 1),
               (char*)Vs + (w * 256 + i * 64) * 16);
    }
  };

  stageK(0, 0);
  asm volatile("s_waitcnt vmcnt(0)" ::: "memory");
  __builtin_amdgcn_s_barrier();
  asm volatile("" ::: "memory");

  for (int t = 0; t < ntiles; ++t) {
    const int buf = t & 1;
    const int kv0 = t << 6;
    const bool active = (kv0 <= q0w + 31);
    stageV(t);                                           // 4 loads
    stageK(buf ^ 1, (t + 1 < ntiles) ? t + 1 : t);       // 4 loads (dummy last)
    if (active) {
      f32x4 s[2][4] = {};
#pragma unroll
      for (int ks = 0; ks < 4; ++ks)
#pragma unroll
        for (int n = 0; n < 4; ++n) {
          int row = n * 16 + l16;
          int off = row * 256 + ((ks * 64 + lh * 16) ^ ((row & 7) << 4));
          bf16x8 kb = *(const bf16x8*)((const char*)Ks[buf] + off);
#pragma unroll
          for (int m = 0; m < 2; ++m) s[m][n] = mfma16(aq[m][ks], kb, s[m][n]);
        }
      if (kv0 + 63 > q0w) {
#pragma unroll
        for (int m = 0; m < 2; ++m)
#pragma unroll
          for (int n = 0; n < 4; ++n)
#pragma unroll
            for (int r = 0; r < 4; ++r) {
              int col = kv0 + n * 16 + l16;
              int rowg = q0w + m * 16 + lh * 4 + r;
              if (col > rowg) s[m][n][r] = -1e30f;
            }
      }
      float lm[2][4];
      bool okl = true;
#pragma unroll
      for (int m = 0; m < 2; ++m)
#pragma unroll
        for (int r = 0; r < 4; ++r) {
          lm[m][r] = fmaxf(fmaxf(s[m][0][r], s[m][1][r]), fmaxf(s[m][2][r], s[m][3][r]));
          okl = okl && (lm[m][r] <= mrow[m][r] + 8.f);
        }
      if (!__all(okl)) {
#pragma unroll
        for (int st = 1; st < 16; st <<= 1)
#pragma unroll
          for (int m = 0; m < 2; ++m)
#pragma unroll
            for (int r = 0; r < 4; ++r) lm[m][r] = fmaxf(lm[m][r], __shfl_xor(lm[m][r], st));
#pragma unroll
        for (int m = 0; m < 2; ++m)
#pragma unroll
          for (int r = 0; r < 4; ++r) {
            float mn = fmaxf(mrow[m][r], lm[m][r]);
            float resc = exp2f(mrow[m][r] - mn);
            mrow[m][r] = mn;
            lrow[m][r] *= resc;
#pragma unroll
            for (int dt = 0; dt < 8; ++dt) acc[m][dt][r] *= resc;
          }
      }
#pragma unroll
      for (int m = 0; m < 2; ++m)
#pragma unroll
        for (int n = 0; n < 4; ++n)
#pragma unroll
          for (int r = 0; r < 4; ++r) {
            float p = exp2f(s[m][n][r] - mrow[m][r]);
            s[m][n][r] = p;
            int row = m * 16 + lh * 4 + r;
            *(bf16*)((char*)Ps[w] + row * 128 +
                     ((n * 32 + l16 * 2) ^ ((row & 7) << 4))) = (bf16)p;
          }
#pragma unroll
      for (int m = 0; m < 2; ++m)
#pragma unroll
        for (int r = 0; r < 4; ++r)
          lrow[m][r] += s[m][0][r] + s[m][1][r] + s[m][2][r] + s[m][3][r];
    }
    asm volatile("s_waitcnt vmcnt(4)" ::: "memory");  // V resident; K(t+1) flying
    __builtin_amdgcn_s_barrier();
    asm volatile("" ::: "memory");
    if (active) {
      bf16x8 pa[2][2];
#pragma unroll
      for (int m = 0; m < 2; ++m)
#pragma unroll
        for (int kf = 0; kf < 2; ++kf) {
          int row = m * 16 + l16;
          pa[m][kf] = *(const bf16x8*)((const char*)Ps[w] + row * 128 +
                                       ((kf * 64 + lh * 16) ^ ((row & 7) << 4)));
        }
#pragma unroll
      for (int kf = 0; kf < 2; ++kf)
#pragma unroll
        for (int dt = 0; dt < 8; ++dt) {
          int d = dt * 16 + l16;
          int off = d * 128 + ((kf * 64 + lh * 16) ^ ((d & 7) << 4));
          bf16x8 vb = *(const bf16x8*)((const char*)Vs + off);
#pragma unroll
          for (int m = 0; m < 2; ++m) acc[m][dt] = mfma16(pa[m][kf], vb, acc[m][dt]);
        }
    }
    asm volatile("s_waitcnt vmcnt(0)" ::: "memory");  // K(t+1) resident
    __builtin_amdgcn_s_barrier();
    asm volatile("" ::: "memory");
  }

#pragma unroll
  for (int st = 1; st < 16; st <<= 1)
#pragma unroll
    for (int m = 0; m < 2; ++m)
#pragma unroll
      for (int r = 0; r < 4; ++r) lrow[m][r] += __shfl_xor(lrow[m][r], st);
  float inv[2][4];
#pragma unroll
  for (int m = 0; m < 2; ++m)
#pragma unroll
    for (int r = 0; r < 4; ++r) inv[m][r] = 1.f / lrow[m][r];
#pragma unroll
  for (int m = 0; m < 2; ++m)
#pragma unroll
    for (int dt = 0; dt < 8; ++dt)
#pragma unroll
      for (int r = 0; r < 4; ++r) {
        int rowg = q0w + m * 16 + lh * 4 + r;
        long long row = (long long)b * S + rowg;
        int col = h * HD + dt * 16 + l16;
        float gv = (float)gate[row * ldg + col];
        outc[row * ldo + col] = (bf16)(acc[m][dt][r] * inv[m][r] * gv);
      }
}

extern "C" void kernel_launch(void* const* d_in, const int* in_sizes, int n_in,
                              void* d_out, int out_size, void* d_ws, size_t ws_size,
                              hipStream_t stream) {
  const float* x = (const float*)d_in[0];
  const float* cosT = (const float*)d_in[2];
  const float* sinT = (const float*)d_in[3];
  const float* wq = (const float*)d_in[4];
  const float* wk = (const float*)d_in[5];
  const float* wv = (const float*)d_in[6];
  const float* wg = (const float*)d_in[7];
  const float* wo = (const float*)d_in[8];
  const float* qs = (const float*)d_in[9];
  const float* ksc = (const float*)d_in[10];
  float* out = (float*)d_out;
  char* ws = (char*)d_ws;

  if (ws_size < 146800640) return;
  bf16* xb = (bf16*)(ws);
  bf16* wcat = (bf16*)(ws + 33554432);
  bf16* woT = (bf16*)(ws + 54525952);
  bf16* C1 = (bf16*)(ws + 62914560);
  bf16* qbuf = xb;
  bf16* kbuf = wcat;
  bf16* vtbuf = wcat + 4194304;
  bf16* gatep = C1 + 3072;
  bf16* ctxg = C1;

  // 1. pre: x->bf16 + all weight transposes (one launch)
  k_pre<<<dim3(64, 64, 6), dim3(32, 8), 0, stream>>>(x, wq, wk, wv, wg, wo, xb,
                                                     wcat, woT);
  // 2. fused QKVG GEMM + sigmoid on gate cols (>=3072)
  k_gemm256<bf16, true><<<32 * 20, 512, 0, stream>>>(
      xb, 2048, wcat, 2048, C1, 5120, 8192, 5120, 2048, 3072);
  // 3. post: RMSNorm+RoPE (Q,K) + V->V^T (one launch)
  k_post<<<45056, 256, 0, stream>>>(C1, qs, ksc, cosT, sinT, qbuf, kbuf, vtbuf);
  // 4. flash attention v5 + gate -> C1 cols 0:2048
  k_flash5<<<1024, 256, 0, stream>>>(qbuf, kbuf, vtbuf, gatep, 5120, ctxg, 5120);
  // 5. output GEMM
  k_gemm256<float, false><<<32 * 8, 512, 0, stream>>>(
      ctxg, 5120, woT, 2048, out, 2048, 8192, 2048, 2048, 1 << 30);
}